// Round 6
// baseline (338.233 us; speedup 1.0000x reference)
//
#include <hip/hip_runtime.h>
#include <hip/hip_bf16.h>
#include <stdint.h>

#define B_ 4
#define N_ 2048
#define D_ 1024
#define K_ 16
#define MROWS (B_*N_)      // 8192
#define NC_ 32
#define CLEN_ (N_/NC_)     // 64

typedef unsigned short u16;
typedef __attribute__((ext_vector_type(8))) short bf16x8;
typedef __attribute__((ext_vector_type(4))) float f32x4;

__device__ __forceinline__ u16 f2bf(float f) {
  uint32_t u = __float_as_uint(f);
  u = u + 0x7fffu + ((u >> 16) & 1u);
  return (u16)(u >> 16);
}

// ---------------- cast fp32 -> bf16 (vectorized) ----------------
__global__ __launch_bounds__(256) void cast_kernel(const float* __restrict__ in,
                                                   u16* __restrict__ out, int n) {
  int i = (blockIdx.x * 256 + threadIdx.x) * 4;
  if (i >= n) return;
  float4 v = *(const float4*)(in + i);
  ushort4 o;
  o.x = f2bf(v.x); o.y = f2bf(v.y); o.z = f2bf(v.z); o.w = f2bf(v.w);
  *(ushort4*)(out + i) = o;
}

// ---------------- fine-phase (K32) pipelined bf16 GEMM ----------------
// C[m,n] = sum_k A[m,k] * W[n,k].  M=8192, K=1024.
// BM=256, BN=FC*64 (FC=4 fused: 256; FC=2 o-proj: 128).
// 512 threads = 8 waves (2 Mrows x 4 Ncols); wave tile 128 x FC*16.
// 32 phases; phase k: tile t=k>>1, K-half kp=k&1 (K32).
// Per phase: STAGE(t+1, kp) [4|3 glds] -> 12|10 ds_read_b128 ->
//   lgkm(4)+schedbar -> 16|8 MFMA (prio1) -> lgkm(0) -> 16|8 MFMA ->
//   vmcnt(4|3) [proves S[k-1]; S[k] stays in flight] -> s_barrier.
// LDS layout per matrix: [slot][khalf][rows][64B], chunk c ^= (row>>1)&3:
//   bank-floor-optimal (8 distinct 16B slots per 16 rows -> all 32 banks
//   at the b128 8-deep minimum; zero true conflicts).  Stage source applies
//   the same involution within each 64B line (coalescing preserved).
#define GL_LDS(gp, lp) \
  __builtin_amdgcn_global_load_lds( \
      (const __attribute__((address_space(1))) void*)(gp), \
      (__attribute__((address_space(3))) void*)(lp), 16, 0, 0)

#define WAITVM(n)  asm volatile("s_waitcnt vmcnt(" #n ")" ::: "memory")
#define WAITLG(n)  asm volatile("s_waitcnt lgkmcnt(" #n ")" ::: "memory")
#define SCHEDB()   __builtin_amdgcn_sched_barrier(0)

template<int FC, bool FUSED>
__global__ __launch_bounds__(512, 2) void gemm_phase(const u16* __restrict__ A,
                                                     const u16* __restrict__ W0,
                                                     const u16* __restrict__ W1,
                                                     float* __restrict__ C0,
                                                     float* __restrict__ C1) {
  constexpr int BROWS = FC * 64;          // B panel rows (output cols per block)
  constexpr int BSLOT = BROWS * 128;      // bytes per B slot (2 khalves)
  constexpr int BKP   = BSLOT / 2;        // bytes per B khalf
  constexpr int BBASE = 65536;            // B region base (A: 2 slots x 32KB)
  __shared__ __align__(16) char lds[BBASE + 2 * BSLOT];

  const int tid = threadIdx.x;
  const int w = tid >> 6, l = tid & 63;
  const int wr = w >> 2, wc = w & 3;      // wave row (0..1), col (0..3)

  // XCD-chunked bijective swizzle, grid 256 (32 per XCD)
  const int orig = blockIdx.x;
  const int wg = (orig & 7) * 32 + (orig >> 3);
  const int bm = wg >> 3;                 // 0..31
  const int bn = wg & 7;                  // 0..7

  const u16* W;
  float* C;
  bool fgate = false;
  int ncol0, colC;
  if (FUSED && bn >= 4) {
    W = W1; C = C1; fgate = true; ncol0 = (bn - 4) * 256; colC = ncol0;
  } else {
    W = W0; C = C0; ncol0 = bn * BROWS; colC = ncol0;
  }

  // ---- staging: group g covers rows g*16..g*16+15 (1KB per gld) ----
  // lane l: row = g*16 + (l>>2), LDS chunk = l&3, src chunk = (l&3)^((l>>3)&3)
  const int srow = l >> 2;
  const int sxc  = ((l & 3) ^ ((l >> 3) & 3)) * 8;   // src k-elem offset
  const u16* aSt0 = A + (size_t)(bm * 256 + (w + 0) * 16 + srow) * 1024 + sxc;
  const u16* aSt1 = A + (size_t)(bm * 256 + (w + 8) * 16 + srow) * 1024 + sxc;
  const u16* bSt0 = W + (size_t)(ncol0 + (w + 0) * 16 + srow) * 1024 + sxc;
  const u16* bSt1 = W + (size_t)(ncol0 + (w + 8) * 16 + srow) * 1024 + sxc; // FC==4 only
  const int aD0 = (w + 0) * 1024 + l * 16;
  const int aD1 = (w + 8) * 1024 + l * 16;

#define STAGE(tt, kpp, sd) do { \
    const size_t go = (size_t)(tt) * 64 + (kpp) * 32; \
    GL_LDS(aSt0 + go, lds + (sd) * 32768 + (kpp) * 16384 + aD0); \
    GL_LDS(aSt1 + go, lds + (sd) * 32768 + (kpp) * 16384 + aD1); \
    GL_LDS(bSt0 + go, lds + BBASE + (sd) * BSLOT + (kpp) * BKP + aD0); \
    if (FC == 4) { GL_LDS(bSt1 + go, lds + BBASE + (sd) * BSLOT + (kpp) * BKP + aD1); } \
  } while (0)

  // ---- fragment reads: row-major 64B rows, chunk = (l>>4) ^ ((row>>1)&3);
  // for all frags (row>>1)&3 == (l>>1)&3  -> lane-constant byte offset
  const int cxa = (((l >> 4) & 3) ^ ((l >> 1) & 3)) * 16;
  const int aRd = wr * 8192 + (l & 15) * 64 + cxa;                  // + fr*1024
  const int bRd = BBASE + wc * (FC * 16) * 64 + (l & 15) * 64 + cxa; // + fc*1024

  f32x4 acc[8][FC] = {};

  // prologue: stage both K-halves of tile 0 into slot 0
  STAGE(0, 0, 0);
  STAGE(0, 1, 0);
  if (FC == 4) { WAITVM(4); } else { WAITVM(3); }
  __builtin_amdgcn_s_barrier();
  SCHEDB();

#pragma unroll
  for (int k = 0; k < 32; ++k) {
    const int t = k >> 1, kp = k & 1, slot = t & 1;
    if (k + 2 < 32) STAGE(t + 1, kp, (t + 1) & 1);

    const char* SA = lds + slot * 32768 + kp * 16384;
    const char* SB = lds + slot * BSLOT + kp * BKP;
    bf16x8 aF[8], bF[FC];
#pragma unroll
    for (int fr = 0; fr < 4; ++fr) aF[fr] = *(const bf16x8*)(SA + aRd + fr * 1024);
#pragma unroll
    for (int fc = 0; fc < FC; ++fc) bF[fc] = *(const bf16x8*)(SB + bRd + fc * 1024);
#pragma unroll
    for (int fr = 4; fr < 8; ++fr) aF[fr] = *(const bf16x8*)(SA + aRd + fr * 1024);

    WAITLG(4); SCHEDB();
    __builtin_amdgcn_s_setprio(1);
#pragma unroll
    for (int fr = 0; fr < 4; ++fr)
#pragma unroll
      for (int fc = 0; fc < FC; ++fc)
        acc[fr][fc] = __builtin_amdgcn_mfma_f32_16x16x32_bf16(aF[fr], bF[fc], acc[fr][fc], 0, 0, 0);
    __builtin_amdgcn_s_setprio(0);
    WAITLG(0); SCHEDB();
    __builtin_amdgcn_s_setprio(1);
#pragma unroll
    for (int fr = 4; fr < 8; ++fr)
#pragma unroll
      for (int fc = 0; fc < FC; ++fc)
        acc[fr][fc] = __builtin_amdgcn_mfma_f32_16x16x32_bf16(aF[fr], bF[fc], acc[fr][fc], 0, 0, 0);
    __builtin_amdgcn_s_setprio(0);

    if (k < 30) {
      if (FC == 4) { WAITVM(4); } else { WAITVM(3); }
    } else if (k == 30) {
      WAITVM(0);
    }
    if (k < 31) { __builtin_amdgcn_s_barrier(); SCHEDB(); }
  }

  // epilogue: C row = bm*256 + wr*128 + fr*16 + (l>>4)*4 + r; col = colC + wc*FC*16 + fc*16 + (l&15)
  const int orow0 = bm * 256 + wr * 128 + (l >> 4) * 4;
  const int ocol0 = colC + wc * (FC * 16) + (l & 15);
#pragma unroll
  for (int fr = 0; fr < 8; ++fr) {
#pragma unroll
    for (int fc = 0; fc < FC; ++fc) {
#pragma unroll
      for (int r = 0; r < 4; ++r) {
        int row = orow0 + fr * 16 + r;
        int col = ocol0 + fc * 16;
        float v = acc[fr][fc][r];
        if (FUSED && fgate) {
          float ls = (v >= 0.0f) ? -log1pf(expf(-v)) : (v - log1pf(expf(v)));
          v = expf(ls * (1.0f / 16.0f));
        }
        C[(size_t)row * 1024 + col] = v;
      }
    }
  }
#undef STAGE
}

// ---------------- e/s projections ----------------
__global__ __launch_bounds__(256) void es_proj(const float* __restrict__ x,
                                               const float* __restrict__ We,
                                               const float* __restrict__ Ws,
                                               float* __restrict__ e,
                                               float* __restrict__ s) {
  int row = blockIdx.x * 4 + (threadIdx.x >> 6);
  int l = threadIdx.x & 63;
  const float* xr = x + (size_t)row * D_;
  float4 xv[4];
#pragma unroll
  for (int j = 0; j < 4; ++j) xv[j] = *(const float4*)(xr + j * 256 + l * 4);
  float pe[K_], ps[K_];
#pragma unroll
  for (int k = 0; k < K_; ++k) {
    float ae = 0.f, as_ = 0.f;
#pragma unroll
    for (int j = 0; j < 4; ++j) {
      float4 wv = *(const float4*)(We + (size_t)k * D_ + j * 256 + l * 4);
      float4 sv = *(const float4*)(Ws + (size_t)k * D_ + j * 256 + l * 4);
      ae  += xv[j].x * wv.x + xv[j].y * wv.y + xv[j].z * wv.z + xv[j].w * wv.w;
      as_ += xv[j].x * sv.x + xv[j].y * sv.y + xv[j].z * sv.z + xv[j].w * sv.w;
    }
    pe[k] = ae; ps[k] = as_;
  }
#pragma unroll
  for (int k = 0; k < K_; ++k) {
    float ae = pe[k], as_ = ps[k];
    for (int off = 32; off > 0; off >>= 1) {
      ae  += __shfl_down(ae, off);
      as_ += __shfl_down(as_, off);
    }
    if (l == 0) {
      e[(size_t)row * K_ + k] = ae;
      s[(size_t)row * K_ + k] = as_;
    }
  }
}

// ---------------- scan pass1 ----------------
__global__ __launch_bounds__(256) void scan_pass1(const float* __restrict__ ibuf,
                                                  const float* __restrict__ fbuf,
                                                  const float* __restrict__ ebuf,
                                                  float* __restrict__ Asc,
                                                  float* __restrict__ Psc) {
  int bid = blockIdx.x;
  int dq = bid & 3, c = (bid >> 2) & (NC_ - 1), b = bid >> 7;
  int d = dq * 256 + threadIdx.x;
  int t0 = c * CLEN_;
  float m[K_];
#pragma unroll
  for (int k = 0; k < K_; ++k) m[k] = 0.f;
  float p = 1.0f;
  const float* ip = ibuf + ((size_t)b * N_ + t0) * D_ + d;
  const float* fp = fbuf + ((size_t)b * N_ + t0) * D_ + d;
  const float* ep = ebuf + ((size_t)b * N_ + t0) * K_;
  for (int t = 0; t < CLEN_; ++t) {
    float it = ip[(size_t)t * D_];
    float ft = fp[(size_t)t * D_];
    p *= ft;
#pragma unroll
    for (int k = 0; k < K_; ++k) m[k] = ft * m[k] + ep[t * K_ + k] * it;
  }
  float* ap = Asc + (((size_t)b * NC_ + c) * K_) * D_ + d;
#pragma unroll
  for (int k = 0; k < K_; ++k) ap[(size_t)k * D_] = m[k];
  Psc[((size_t)b * NC_ + c) * D_ + d] = p;
}

// ---------------- scan pass2 ----------------
__global__ __launch_bounds__(256) void scan_pass2(const float* __restrict__ Asc,
                                                  const float* __restrict__ Psc,
                                                  float* __restrict__ Ssc) {
  int idx = blockIdx.x * 256 + threadIdx.x;
  int d = idx & (D_ - 1);
  int k = (idx >> 10) & (K_ - 1);
  int b = idx >> 14;
  float M = 0.f;
  for (int c = 0; c < NC_; ++c) {
    size_t base = (((size_t)b * NC_ + c) * K_ + k) * D_ + d;
    float a = Asc[base];
    float pp = Psc[((size_t)b * NC_ + c) * D_ + d];
    Ssc[base] = M;
    M = pp * M + a;
  }
}

// ---------------- scan pass3 ----------------
__global__ __launch_bounds__(256) void scan_pass3(float* __restrict__ ibuf,
                                                  const float* __restrict__ fbuf,
                                                  const float* __restrict__ ebuf,
                                                  const float* __restrict__ sbuf,
                                                  const float* __restrict__ Ssc) {
  int bid = blockIdx.x;
  int dq = bid & 3, c = (bid >> 2) & (NC_ - 1), b = bid >> 7;
  int d = dq * 256 + threadIdx.x;
  int t0 = c * CLEN_;
  float m[K_];
  const float* sp0 = Ssc + (((size_t)b * NC_ + c) * K_) * D_ + d;
#pragma unroll
  for (int k = 0; k < K_; ++k) m[k] = sp0[(size_t)k * D_];
  float* ip = ibuf + ((size_t)b * N_ + t0) * D_ + d;
  const float* fp = fbuf + ((size_t)b * N_ + t0) * D_ + d;
  const float* ep = ebuf + ((size_t)b * N_ + t0) * K_;
  const float* zp = sbuf + ((size_t)b * N_ + t0) * K_;
  for (int t = 0; t < CLEN_; ++t) {
    float it = ip[(size_t)t * D_];
    float ft = fp[(size_t)t * D_];
    float y = 0.f;
#pragma unroll
    for (int k = 0; k < K_; ++k) {
      m[k] = ft * m[k] + ep[t * K_ + k] * it;
      y += zp[t * K_ + k] * m[k];
    }
    ip[(size_t)t * D_] = y;
  }
}

// ---------------- LayerNorm -> bf16 ----------------
__global__ __launch_bounds__(256) void ln_kernel(const float* __restrict__ y,
                                                 const float* __restrict__ gamma,
                                                 const float* __restrict__ beta,
                                                 u16* __restrict__ yn) {
  int row = blockIdx.x * 4 + (threadIdx.x >> 6);
  int l = threadIdx.x & 63;
  const float* yr = y + (size_t)row * D_;
  float4 v[4];
  float sum = 0.f;
#pragma unroll
  for (int j = 0; j < 4; ++j) {
    v[j] = *(const float4*)(yr + j * 256 + l * 4);
    sum += v[j].x + v[j].y + v[j].z + v[j].w;
  }
  for (int off = 32; off > 0; off >>= 1) sum += __shfl_xor(sum, off);
  float mu = sum * (1.0f / D_);
  float vs = 0.f;
#pragma unroll
  for (int j = 0; j < 4; ++j) {
    float dx = v[j].x - mu; vs += dx * dx;
    dx = v[j].y - mu; vs += dx * dx;
    dx = v[j].z - mu; vs += dx * dx;
    dx = v[j].w - mu; vs += dx * dx;
  }
  for (int off = 32; off > 0; off >>= 1) vs += __shfl_xor(vs, off);
  float rstd = rsqrtf(vs * (1.0f / D_) + 1e-5f);
#pragma unroll
  for (int j = 0; j < 4; ++j) {
    int col = j * 256 + l * 4;
    float4 g = *(const float4*)(gamma + col);
    float4 bt = *(const float4*)(beta + col);
    ushort4 o;
    o.x = f2bf((v[j].x - mu) * rstd * g.x + bt.x);
    o.y = f2bf((v[j].y - mu) * rstd * g.y + bt.y);
    o.z = f2bf((v[j].z - mu) * rstd * g.z + bt.z);
    o.w = f2bf((v[j].w - mu) * rstd * g.w + bt.w);
    *(ushort4*)(yn + (size_t)row * D_ + col) = o;
  }
}

extern "C" void kernel_launch(void* const* d_in, const int* in_sizes, int n_in,
                              void* d_out, int out_size, void* d_ws, size_t ws_size,
                              hipStream_t stream) {
  const float* x     = (const float*)d_in[0];
  const float* Wi    = (const float*)d_in[1];
  const float* We    = (const float*)d_in[2];
  const float* Wf    = (const float*)d_in[3];
  const float* Ws    = (const float*)d_in[4];
  const float* gamma = (const float*)d_in[5];
  const float* beta  = (const float*)d_in[6];
  const float* Wo    = (const float*)d_in[7];
  float* out = (float*)d_out;

  char* p = (char*)d_ws;
  u16* xb  = (u16*)p;  p += (size_t)MROWS * D_ * 2;
  u16* wib = (u16*)p;  p += (size_t)D_ * D_ * 2;
  u16* wfb = (u16*)p;  p += (size_t)D_ * D_ * 2;
  u16* wob = (u16*)p;  p += (size_t)D_ * D_ * 2;
  float* ibuf = (float*)p; p += (size_t)MROWS * D_ * 4;
  float* fbuf = (float*)p; p += (size_t)MROWS * D_ * 4;
  float* ebuf = (float*)p; p += (size_t)MROWS * K_ * 4;
  float* sbuf = (float*)p; p += (size_t)MROWS * K_ * 4;
  float* Asc  = (float*)p; p += (size_t)B_ * NC_ * K_ * D_ * 4;
  float* Ssc  = (float*)p; p += (size_t)B_ * NC_ * K_ * D_ * 4;
  float* Psc  = (float*)p; p += (size_t)B_ * NC_ * D_ * 4;

  cast_kernel<<<MROWS * D_ / 1024, 256, 0, stream>>>(x, xb, MROWS * D_);
  cast_kernel<<<D_ * D_ / 1024, 256, 0, stream>>>(Wi, wib, D_ * D_);
  cast_kernel<<<D_ * D_ / 1024, 256, 0, stream>>>(Wf, wfb, D_ * D_);
  cast_kernel<<<D_ * D_ / 1024, 256, 0, stream>>>(Wo, wob, D_ * D_);

  // fused i+f projection: 256 blocks x 512 threads, fine-phase pipeline
  gemm_phase<4, true><<<256, 512, 0, stream>>>(xb, wib, wfb, ibuf, fbuf);

  es_proj<<<MROWS / 4, 256, 0, stream>>>(x, We, Ws, ebuf, sbuf);

  scan_pass1<<<B_ * NC_ * 4, 256, 0, stream>>>(ibuf, fbuf, ebuf, Asc, Psc);
  scan_pass2<<<B_ * K_ * D_ / 256, 256, 0, stream>>>(Asc, Psc, Ssc);
  scan_pass3<<<B_ * NC_ * 4, 256, 0, stream>>>(ibuf, fbuf, ebuf, sbuf, Ssc);

  u16* ynb = xb;
  ln_kernel<<<MROWS / 4, 256, 0, stream>>>(ibuf, gamma, beta, ynb);

  // o-proj: BN=128 variant, 256 blocks
  gemm_phase<2, false><<<256, 512, 0, stream>>>(ynb, wob, nullptr, out, nullptr);
}